// Round 6
// 1222.160 us; speedup vs baseline: 1.3860x; 1.3860x over previous
//
#include <hip/hip_runtime.h>

typedef unsigned short u16;
typedef __bf16 bf16x8 __attribute__((ext_vector_type(8)));
typedef float f32x4 __attribute__((ext_vector_type(4)));

#define LOG2E 1.44269504089f

// ---------- bf16 helpers (manual RNE; inputs are finite) ----------
__device__ __forceinline__ u16 f2b(float f) {
  unsigned u = __builtin_bit_cast(unsigned, f);
  u += 0x7fffu + ((u >> 16) & 1u);
  return (u16)(u >> 16);
}
__device__ __forceinline__ float b2f(u16 h) {
  unsigned u = ((unsigned)h) << 16;
  return __builtin_bit_cast(float, u);
}
__device__ __forceinline__ f32x4 mfma_bf16(bf16x8 a, bf16x8 b, f32x4 c) {
  return __builtin_amdgcn_mfma_f32_16x16x32_bf16(a, b, c, 0, 0, 0);
}
// async global->LDS, 16B per lane; LDS dest must be wave-uniform base + lane*16
__device__ __forceinline__ void gload16(const void* g, void* l) {
  __builtin_amdgcn_global_load_lds(
      (const __attribute__((address_space(1))) unsigned int*)g,
      (__attribute__((address_space(3))) unsigned int*)l, 16, 0, 0);
}

// ---------- split x (fp32 -> hi/lo bf16), 4 elems/thread ----------
__global__ __launch_bounds__(256) void split_kernel(const float* __restrict__ x,
                                                    u16* __restrict__ xh,
                                                    u16* __restrict__ xl) {
  int i = blockIdx.x * 256 + threadIdx.x;
  float4 v = ((const float4*)x)[i];
  ushort4 h, l;
  h.x = f2b(v.x); l.x = f2b(v.x - b2f(h.x));
  h.y = f2b(v.y); l.y = f2b(v.y - b2f(h.y));
  h.z = f2b(v.z); l.z = f2b(v.z - b2f(h.z));
  h.w = f2b(v.w); l.w = f2b(v.w - b2f(h.w));
  ((ushort4*)xh)[i] = h;
  ((ushort4*)xl)[i] = l;
}

// ---------- transpose W[k][n] -> WT[n][k] bf16 (optionally hi/lo split) ----------
template <bool SPLIT>
__global__ __launch_bounds__(256) void transpose_kernel(const float* __restrict__ W,
                                                        u16* __restrict__ WhT,
                                                        u16* __restrict__ WlT) {
  __shared__ float tile[32][33];
  int tx = threadIdx.x & 31, ty = threadIdx.x >> 5;
  int n0 = blockIdx.x * 32, k0 = blockIdx.y * 32;
#pragma unroll
  for (int i = 0; i < 4; ++i)
    tile[ty + i * 8][tx] = W[(size_t)(k0 + ty + i * 8) * 2048 + n0 + tx];
  __syncthreads();
#pragma unroll
  for (int i = 0; i < 4; ++i) {
    int n = ty + i * 8;
    float v = tile[tx][n];
    u16 hv = f2b(v);
    WhT[(size_t)(n0 + n) * 2048 + k0 + tx] = hv;
    if constexpr (SPLIT)
      WlT[(size_t)(n0 + n) * 2048 + k0 + tx] = f2b(v - b2f(hv));
  }
}

// ---------- GEMM: C[4096][2048] = A[4096][2048] @ B^T[2048][2048] (+bias)*scale ----------
// SPLIT: A=Ah+Al, B=Bh+Bl, acc = Ah*Bh + Ah*Bl + Al*Bh (drops l*l, ~fp32 accurate)
// OUT_MODE: 0 = fp32 row-major, 1 = bf16 row-major, 2 = bf16 transposed to [b,h,d,s]
//           3 = bf16 hi/lo split pair, row-major (Cb = hi, Cb2 = lo)
template <bool SPLIT, int OUT_MODE>
__global__ __launch_bounds__(256) void gemm_kernel(
    const u16* __restrict__ Ah, const u16* __restrict__ Al,
    const u16* __restrict__ Bh, const u16* __restrict__ Bl,
    const float* __restrict__ bias, float scale,
    float* __restrict__ Cf, u16* __restrict__ Cb, u16* __restrict__ Cb2) {
  __shared__ __align__(16) u16 smem[SPLIT ? 16384 : 8192];
  u16* sAh = smem;
  u16* sBh = smem + 4096;
  u16* sAl = smem + 8192;   // used only if SPLIT
  u16* sBl = smem + 12288;  // used only if SPLIT
  const int t = threadIdx.x;
  const int lane = t & 63, w = t >> 6;
  const int wr = w >> 1, wc = w & 1;
  const int quad = lane >> 4, l16 = lane & 15;
  const int m0 = blockIdx.y * 128, n0 = blockIdx.x * 128;

  f32x4 acc[4][4] = {};

  for (int kt = 0; kt < 64; ++kt) {  // K = 2048 / BK(32)
#pragma unroll
    for (int j = 0; j < 2; ++j) {
      int c = t + 256 * j;           // 512 chunks of 16B per 128x32 tile
      int row = c >> 2, cw = c & 3;
      size_t goff = (size_t)row * 2048 + kt * 32 + cw * 8;
      gload16(Ah + (size_t)m0 * 2048 + goff, (char*)sAh + c * 16);
      gload16(Bh + (size_t)n0 * 2048 + goff, (char*)sBh + c * 16);
      if constexpr (SPLIT) {
        gload16(Al + (size_t)m0 * 2048 + goff, (char*)sAl + c * 16);
        gload16(Bl + (size_t)n0 * 2048 + goff, (char*)sBl + c * 16);
      }
    }
    __syncthreads();
    bf16x8 ah[4], bh[4], al[4], bl[4];
#pragma unroll
    for (int i = 0; i < 4; ++i) {
      int ar = (wr * 64 + i * 16 + l16) * 32 + quad * 8;
      int br = (wc * 64 + i * 16 + l16) * 32 + quad * 8;
      ah[i] = *(const bf16x8*)&sAh[ar];
      bh[i] = *(const bf16x8*)&sBh[br];
      if constexpr (SPLIT) {
        al[i] = *(const bf16x8*)&sAl[ar];
        bl[i] = *(const bf16x8*)&sBl[br];
      }
    }
#pragma unroll
    for (int mi = 0; mi < 4; ++mi)
#pragma unroll
      for (int ni = 0; ni < 4; ++ni) {
        acc[mi][ni] = mfma_bf16(ah[mi], bh[ni], acc[mi][ni]);
        if constexpr (SPLIT) {
          acc[mi][ni] = mfma_bf16(ah[mi], bl[ni], acc[mi][ni]);
          acc[mi][ni] = mfma_bf16(al[mi], bh[ni], acc[mi][ni]);
        }
      }
    __syncthreads();
  }

#pragma unroll
  for (int mi = 0; mi < 4; ++mi) {
    int rowb = m0 + wr * 64 + mi * 16 + quad * 4;
#pragma unroll
    for (int ni = 0; ni < 4; ++ni) {
      int col = n0 + wc * 64 + ni * 16 + l16;
      float bv = bias[col];
#pragma unroll
      for (int r = 0; r < 4; ++r) {
        float v = (acc[mi][ni][r] + bv) * scale;
        int row = rowb + r;
        if constexpr (OUT_MODE == 0) {
          Cf[(size_t)row * 2048 + col] = v;
        } else if constexpr (OUT_MODE == 1) {
          Cb[(size_t)row * 2048 + col] = f2b(v);
        } else if constexpr (OUT_MODE == 2) {
          // V transposed: [b][h][d][s], b=row>>11, s=row&2047, h=col>>7, d=col&127
          int b_ = row >> 11, s_ = row & 2047, h_ = col >> 7, d_ = col & 127;
          Cb[((size_t)((b_ * 16 + h_) * 128 + d_) << 11) + s_] = f2b(v);
        } else {
          u16 hv = f2b(v);
          Cb[(size_t)row * 2048 + col] = hv;
          Cb2[(size_t)row * 2048 + col] = f2b(v - b2f(hv));
        }
      }
    }
  }
}

// ---------- flash attention v2 ----------
// Bq=64 (4 waves x 16 q-rows), Bk=32/iter. Q hi/lo in REGISTERS (pre-split by GEMM).
// K hi/lo + V staged via global_load_lds with XOR-swizzled SOURCE addresses
// (linear LDS dest, swizzled ds_read -> conflict-free), double-buffered, 1 barrier/iter.
// QK^T swapped (A=K, B=Q): lane holds 8 scores of ONE q-row -> row-max = 7 fmax + 2 shfl;
// row-sum via one MFMA against a ones vector. Defer-max rescale (THR = 8 nats).
__global__ __launch_bounds__(256, 3) void attn_kernel(
    const u16* __restrict__ Qh, const u16* __restrict__ Ql,
    const u16* __restrict__ Kh, const u16* __restrict__ Kl,
    const u16* __restrict__ VT, const float* __restrict__ bias,
    u16* __restrict__ ctx) {
  // LDS bytes: K[2 buf][hi 8K | lo 8K] = 32768 | V[2 buf][8K] = 16384 | P [64][40] = 5120
  __shared__ __align__(16) u16 sm[27136];  // 54272 B -> 3 blocks/CU
  const int t = threadIdx.x, lane = t & 63, w = t >> 6;
  const int quad = lane >> 4, l16 = lane & 15;
  const int bh = blockIdx.y, b = bh >> 4, h = bh & 15;
  const int q0 = blockIdx.x * 64;

  // ---- Q fragments in registers (lane's q-row = w*16 + l16) ----
  bf16x8 qh[4], ql[4];
  {
    const size_t qoff =
        (size_t)(b * 2048 + q0 + w * 16 + l16) * 2048 + h * 128 + quad * 8;
#pragma unroll
    for (int ks = 0; ks < 4; ++ks) {
      qh[ks] = *(const bf16x8*)&Qh[qoff + ks * 32];
      ql[ks] = *(const bf16x8*)&Ql[qoff + ks * 32];
    }
  }

  // ---- per-thread staging source bases (swizzle folded into GLOBAL address) ----
  // K tile: 32 rows x 256B, 16 chunks/row; phys chunk p holds logical p ^ (row&7)
  const int kr = t >> 4, kp = (t & 15) ^ (kr & 7);
  const u16* gK = Kh + ((size_t)b * 2048) * 2048 + h * 128 + (size_t)kr * 2048 + kp * 8;
  // V tile: 128 rows x 64B, 4 chunks/row; phys chunk p holds logical p ^ ((row>>1)&3)
  const int vr = t >> 2, vp = (t & 3) ^ ((vr >> 1) & 3);
  const u16* gV = VT + (size_t)bh * 128 * 2048 + (size_t)vr * 2048 + vp * 8;

  auto stage = [&](int bf, int kt) {
    const u16* pk = gK + (size_t)kt * 65536;  // +32 rows
    const u16* pv = gV + kt * 32;             // +32 cols
    char* bK = (char*)sm + bf * 16384;
    char* bV = (char*)sm + 32768 + bf * 8192;
    gload16(pk, bK + t * 16);                      // K hi rows 0..15
    gload16(pk + 32768, bK + 4096 + t * 16);       // K hi rows 16..31
    gload16(pk + 8388608, bK + 8192 + t * 16);     // K lo rows 0..15 (Kl = Kh + 8M elems)
    gload16(pk + 8421376, bK + 12288 + t * 16);    // K lo rows 16..31
    gload16(pv, bV + t * 16);                      // V rows 0..63
    gload16(pv + 131072, bV + 4096 + t * 16);      // V rows 64..127
  };

  f32x4 o[8] = {};
  f32x4 lacc = {};          // row sums, C-layout (row = quad*4+r) via ones-MFMA
  float m_i = -3e38f;       // running max (log2 domain), per-lane q-row = l16

  const float* biasp = bias + ((size_t)bh * 2048 + q0 + w * 16 + l16) * 2048;
  bf16x8 ones;
#pragma unroll
  for (int i = 0; i < 8; ++i) ones[i] = __builtin_bit_cast(__bf16, (u16)0x3F80);
  u16* sP = sm + 24576;

  stage(0, 0);
  int buf = 0;

  for (int kt = 0; kt < 64; ++kt) {
    __syncthreads();                       // staging of buf complete; buf^1 free
    if (kt + 1 < 64) stage(buf ^ 1, kt + 1);  // async prefetch rides across compute
    const int s0 = kt * 32;

    // bias early (hide latency under QK^T); lane needs k = s0 + ni*16 + quad*4 + r
    float4 b0 = *(const float4*)&biasp[s0 + quad * 4];
    float4 b1 = *(const float4*)&biasp[s0 + 16 + quad * 4];
    float ba[2][4] = {{b0.x, b0.y, b0.z, b0.w}, {b1.x, b1.y, b1.z, b1.w}};

    // QK^T swapped: A = K rows, B = Q rows; C[k = quad*4+r (+16*ni)][q = l16]
    const u16* sKh = sm + buf * 8192;
    const u16* sKl = sKh + 4096;
    f32x4 sc[2] = {};
#pragma unroll
    for (int ni = 0; ni < 2; ++ni) {
      const int rb = (ni * 16 + l16) * 128;
      const int x7 = l16 & 7;
#pragma unroll
      for (int ks = 0; ks < 4; ++ks) {
        int koff = rb + (((ks * 4 + quad) ^ x7) << 3);
        bf16x8 kh = *(const bf16x8*)&sKh[koff];
        bf16x8 kl = *(const bf16x8*)&sKl[koff];
        sc[ni] = mfma_bf16(kh, qh[ks], sc[ni]);
        sc[ni] = mfma_bf16(kl, qh[ks], sc[ni]);
        sc[ni] = mfma_bf16(kh, ql[ks], sc[ni]);
      }
    }

    // online softmax, log2 domain; lane's 8 scores all belong to q-row l16
    float z[2][4], zm = -3e38f;
#pragma unroll
    for (int ni = 0; ni < 2; ++ni)
#pragma unroll
      for (int r = 0; r < 4; ++r) {
        z[ni][r] = (sc[ni][r] + ba[ni][r]) * LOG2E;
        zm = fmaxf(zm, z[ni][r]);
      }
    zm = fmaxf(zm, __shfl_xor(zm, 16));
    zm = fmaxf(zm, __shfl_xor(zm, 32));

    if (__any(zm > m_i + 11.5416f)) {  // defer-max: rescale only on real growth (8 nats)
      float mn = fmaxf(m_i, zm);
      float alpha = exp2f(m_i - mn);   // per-lane, q-row = l16
      m_i = mn;
#pragma unroll
      for (int r = 0; r < 4; ++r) {
        float aC = __shfl(alpha, quad * 4 + r);  // redistribute to C-layout rows
        lacc[r] *= aC;
#pragma unroll
        for (int d = 0; d < 8; ++d) o[d][r] *= aC;
      }
    }

    // P = exp2(z - m), pack 4 k-consecutive values -> one b64 LDS write; sP is [64][40]
    u16* sPw = sP + (w * 16 + l16) * 40 + quad * 4;
#pragma unroll
    for (int ni = 0; ni < 2; ++ni) {
      ushort4 pw;
      pw.x = f2b(exp2f(z[ni][0] - m_i));
      pw.y = f2b(exp2f(z[ni][1] - m_i));
      pw.z = f2b(exp2f(z[ni][2] - m_i));
      pw.w = f2b(exp2f(z[ni][3] - m_i));
      *(ushort4*)&sPw[ni * 16] = pw;
    }

    // PV: A = P rows (wave-local), B = V^T rows (swizzled); l-sum via ones-MFMA
    bf16x8 ap = *(const bf16x8*)&sP[(w * 16 + l16) * 40 + quad * 8];
    lacc = mfma_bf16(ap, ones, lacc);
    const u16* sV = sm + 16384 + buf * 4096;
    const int vx = quad ^ ((l16 >> 1) & 3);
#pragma unroll
    for (int d = 0; d < 8; ++d) {
      bf16x8 bv = *(const bf16x8*)&sV[(d * 16 + l16) * 32 + (vx << 3)];
      o[d] = mfma_bf16(ap, bv, o[d]);
    }
    buf ^= 1;
  }

  float inv[4];
#pragma unroll
  for (int r = 0; r < 4; ++r) inv[r] = 1.f / lacc[r];
#pragma unroll
  for (int d = 0; d < 8; ++d)
#pragma unroll
    for (int r = 0; r < 4; ++r) {
      int qr = w * 16 + quad * 4 + r;
      ctx[((size_t)(b * 2048 + q0 + qr)) * 2048 + h * 128 + d * 16 + l16] =
          f2b(o[d][r] * inv[r]);
    }
}

extern "C" void kernel_launch(void* const* d_in, const int* in_sizes, int n_in,
                              void* d_out, int out_size, void* d_ws, size_t ws_size,
                              hipStream_t stream) {
  (void)in_sizes; (void)n_in; (void)out_size; (void)ws_size;
  const float* x  = (const float*)d_in[0];
  const float* ab = (const float*)d_in[1];
  const float* Wq = (const float*)d_in[2];
  const float* bq = (const float*)d_in[3];
  const float* Wk = (const float*)d_in[4];
  const float* bk = (const float*)d_in[5];
  const float* Wv = (const float*)d_in[6];
  const float* bv = (const float*)d_in[7];
  const float* Wo = (const float*)d_in[8];
  const float* bo = (const float*)d_in[9];
  float* out = (float*)d_out;

  char* ws = (char*)d_ws;
  u16*   Kh  = (u16*)(ws + 0);            // 16.8 MB bf16 K hi (contiguous with lo!)
  u16*   Kl  = (u16*)(ws + 16777216);     // 16.8 MB bf16 K lo  (= Kh + 8388608 elems)
  u16*   VT  = (u16*)(ws + 33554432);     // 16.8 MB bf16 V^T [b,h,d,s]
  u16*   ctx = (u16*)(ws + 50331648);     // 16.8 MB bf16 ctx [m][hid]
  u16*   xh  = (u16*)(ws + 67108864);     // 16.8 MB
  u16*   xl  = (u16*)(ws + 83886080);     // 16.8 MB
  u16*   WhT = (u16*)(ws + 100663296);    // 8.4 MB (reused per projection)
  u16*   WlT = (u16*)(ws + 109051904);    // 8.4 MB
  u16*   Qh  = (u16*)out;                 // park Q hi/lo in d_out (16.8 + 16.8 MB)
  u16*   Ql  = (u16*)out + 8388608;       // overwritten by final GEMM

  const float SCALE = 11.313708499f;  // sqrt(128), multiplies q (faithful to reference)

  split_kernel<<<8192, 256, 0, stream>>>(x, xh, xl);

  transpose_kernel<true><<<dim3(64, 64), 256, 0, stream>>>(Wq, WhT, WlT);
  gemm_kernel<true, 3><<<dim3(16, 32), 256, 0, stream>>>(xh, xl, WhT, WlT, bq, SCALE, nullptr, Qh, Ql);

  transpose_kernel<true><<<dim3(64, 64), 256, 0, stream>>>(Wk, WhT, WlT);
  gemm_kernel<true, 3><<<dim3(16, 32), 256, 0, stream>>>(xh, xl, WhT, WlT, bk, 1.0f, nullptr, Kh, Kl);

  transpose_kernel<false><<<dim3(64, 64), 256, 0, stream>>>(Wv, WhT, nullptr);
  gemm_kernel<false, 2><<<dim3(16, 32), 256, 0, stream>>>(xh, nullptr, WhT, nullptr, bv, 1.0f, nullptr, VT, nullptr);

  attn_kernel<<<dim3(32, 32), 256, 0, stream>>>(Qh, Ql, Kh, Kl, VT, ab, ctx);

  transpose_kernel<false><<<dim3(64, 64), 256, 0, stream>>>(Wo, WhT, nullptr);
  gemm_kernel<false, 0><<<dim3(16, 32), 256, 0, stream>>>(ctx, nullptr, WhT, nullptr, bo, 1.0f, out, nullptr, nullptr);
}

// Round 7
// 1209.648 us; speedup vs baseline: 1.4004x; 1.0103x over previous
//
#include <hip/hip_runtime.h>

typedef unsigned short u16;
typedef __bf16 bf16x8 __attribute__((ext_vector_type(8)));
typedef float f32x4 __attribute__((ext_vector_type(4)));

#define LOG2E 1.44269504089f

// ---------- bf16 helpers (manual RNE; inputs are finite) ----------
__device__ __forceinline__ u16 f2b(float f) {
  unsigned u = __builtin_bit_cast(unsigned, f);
  u += 0x7fffu + ((u >> 16) & 1u);
  return (u16)(u >> 16);
}
__device__ __forceinline__ float b2f(u16 h) {
  unsigned u = ((unsigned)h) << 16;
  return __builtin_bit_cast(float, u);
}
__device__ __forceinline__ f32x4 mfma_bf16(bf16x8 a, bf16x8 b, f32x4 c) {
  return __builtin_amdgcn_mfma_f32_16x16x32_bf16(a, b, c, 0, 0, 0);
}
// async global->LDS, 16B per lane; LDS dest must be wave-uniform base + lane*16
__device__ __forceinline__ void gload16(const void* g, void* l) {
  __builtin_amdgcn_global_load_lds(
      (const __attribute__((address_space(1))) unsigned int*)g,
      (__attribute__((address_space(3))) unsigned int*)l, 16, 0, 0);
}

// ---------- split x (fp32 -> hi/lo bf16), 4 elems/thread ----------
__global__ __launch_bounds__(256) void split_kernel(const float* __restrict__ x,
                                                    u16* __restrict__ xh,
                                                    u16* __restrict__ xl) {
  int i = blockIdx.x * 256 + threadIdx.x;
  float4 v = ((const float4*)x)[i];
  ushort4 h, l;
  h.x = f2b(v.x); l.x = f2b(v.x - b2f(h.x));
  h.y = f2b(v.y); l.y = f2b(v.y - b2f(h.y));
  h.z = f2b(v.z); l.z = f2b(v.z - b2f(h.z));
  h.w = f2b(v.w); l.w = f2b(v.w - b2f(h.w));
  ((ushort4*)xh)[i] = h;
  ((ushort4*)xl)[i] = l;
}

// ---------- fused transpose of all 4 weights: W[k][n] -> WT[n][k] bf16 ----------
// z=0: Wq (hi/lo), z=1: Wk (hi/lo), z=2: Wv (hi only), z=3: Wo (hi only)
__global__ __launch_bounds__(256) void transpose4_kernel(
    const float* __restrict__ Wq, const float* __restrict__ Wk,
    const float* __restrict__ Wv, const float* __restrict__ Wo,
    u16* __restrict__ WqhT, u16* __restrict__ WqlT,
    u16* __restrict__ WkhT, u16* __restrict__ WklT,
    u16* __restrict__ WvhT, u16* __restrict__ WohT) {
  const float* W;
  u16 *Ht, *Lt;
  bool split;
  switch (blockIdx.z) {
    case 0:  W = Wq; Ht = WqhT; Lt = WqlT; split = true;  break;
    case 1:  W = Wk; Ht = WkhT; Lt = WklT; split = true;  break;
    case 2:  W = Wv; Ht = WvhT; Lt = nullptr; split = false; break;
    default: W = Wo; Ht = WohT; Lt = nullptr; split = false; break;
  }
  __shared__ float tile[32][33];
  int tx = threadIdx.x & 31, ty = threadIdx.x >> 5;
  int n0 = blockIdx.x * 32, k0 = blockIdx.y * 32;
#pragma unroll
  for (int i = 0; i < 4; ++i)
    tile[ty + i * 8][tx] = W[(size_t)(k0 + ty + i * 8) * 2048 + n0 + tx];
  __syncthreads();
#pragma unroll
  for (int i = 0; i < 4; ++i) {
    int n = ty + i * 8;
    float v = tile[tx][n];
    u16 hv = f2b(v);
    Ht[(size_t)(n0 + n) * 2048 + k0 + tx] = hv;
    if (split) Lt[(size_t)(n0 + n) * 2048 + k0 + tx] = f2b(v - b2f(hv));
  }
}

// ---------- fused QKV GEMM: grid (16,32,3); z=0:Q(split,hi/lo out) z=1:K(split,hi/lo out)
// z=2:V(non-split, transposed bf16 out). Inner loop identical to the measured gemm_kernel;
// runtime block-uniform `split`. 1536 blocks @ 32KB LDS + <=170 VGPR -> 3 blocks/CU:
// cross-block wave overlap hides the per-K-step barrier drain (m114 mechanism).
__global__ __launch_bounds__(256, 3) void qkv_gemm_kernel(
    const u16* __restrict__ Ah, const u16* __restrict__ Al,
    const u16* __restrict__ WqhT, const u16* __restrict__ WqlT,
    const u16* __restrict__ WkhT, const u16* __restrict__ WklT,
    const u16* __restrict__ WvhT,
    const float* __restrict__ bq, const float* __restrict__ bk,
    const float* __restrict__ bv,
    u16* __restrict__ Qh, u16* __restrict__ Ql,
    u16* __restrict__ Kh, u16* __restrict__ Kl,
    u16* __restrict__ VT) {
  const int z = blockIdx.z;
  const bool split = (z != 2);
  const u16* Bh = (z == 0) ? WqhT : (z == 1) ? WkhT : WvhT;
  const u16* Bl = (z == 0) ? WqlT : WklT;  // unused when z==2
  const float* bias = (z == 0) ? bq : (z == 1) ? bk : bv;
  const float scale = (z == 0) ? 11.313708499f : 1.0f;  // sqrt(128) on Q (faithful)
  u16* Hdst = (z == 0) ? Qh : Kh;
  u16* Ldst = (z == 0) ? Ql : Kl;

  __shared__ __align__(16) u16 smem[16384];
  u16* sAh = smem;
  u16* sBh = smem + 4096;
  u16* sAl = smem + 8192;
  u16* sBl = smem + 12288;
  const int t = threadIdx.x;
  const int lane = t & 63, w = t >> 6;
  const int wr = w >> 1, wc = w & 1;
  const int quad = lane >> 4, l16 = lane & 15;
  const int m0 = blockIdx.y * 128, n0 = blockIdx.x * 128;

  f32x4 acc[4][4] = {};

  for (int kt = 0; kt < 64; ++kt) {  // K = 2048 / BK(32)
#pragma unroll
    for (int j = 0; j < 2; ++j) {
      int c = t + 256 * j;           // 512 chunks of 16B per 128x32 tile
      int row = c >> 2, cw = c & 3;
      size_t goff = (size_t)row * 2048 + kt * 32 + cw * 8;
      gload16(Ah + (size_t)m0 * 2048 + goff, (char*)sAh + c * 16);
      gload16(Bh + (size_t)n0 * 2048 + goff, (char*)sBh + c * 16);
      if (split) {
        gload16(Al + (size_t)m0 * 2048 + goff, (char*)sAl + c * 16);
        gload16(Bl + (size_t)n0 * 2048 + goff, (char*)sBl + c * 16);
      }
    }
    __syncthreads();
    bf16x8 ah[4], bh[4], al[4], bl[4];
#pragma unroll
    for (int i = 0; i < 4; ++i) {
      int ar = (wr * 64 + i * 16 + l16) * 32 + quad * 8;
      int br = (wc * 64 + i * 16 + l16) * 32 + quad * 8;
      ah[i] = *(const bf16x8*)&sAh[ar];
      bh[i] = *(const bf16x8*)&sBh[br];
      if (split) {
        al[i] = *(const bf16x8*)&sAl[ar];
        bl[i] = *(const bf16x8*)&sBl[br];
      }
    }
#pragma unroll
    for (int mi = 0; mi < 4; ++mi)
#pragma unroll
      for (int ni = 0; ni < 4; ++ni) {
        acc[mi][ni] = mfma_bf16(ah[mi], bh[ni], acc[mi][ni]);
        if (split) {
          acc[mi][ni] = mfma_bf16(ah[mi], bl[ni], acc[mi][ni]);
          acc[mi][ni] = mfma_bf16(al[mi], bh[ni], acc[mi][ni]);
        }
      }
    __syncthreads();
  }

#pragma unroll
  for (int mi = 0; mi < 4; ++mi) {
    int rowb = m0 + wr * 64 + mi * 16 + quad * 4;
#pragma unroll
    for (int ni = 0; ni < 4; ++ni) {
      int col = n0 + wc * 64 + ni * 16 + l16;
      float bv_ = bias[col];
#pragma unroll
      for (int r = 0; r < 4; ++r) {
        float v = (acc[mi][ni][r] + bv_) * scale;
        int row = rowb + r;
        if (z == 2) {
          // V transposed: [b][h][d][s], b=row>>11, s=row&2047, h=col>>7, d=col&127
          int b_ = row >> 11, s_ = row & 2047, h_ = col >> 7, d_ = col & 127;
          VT[((size_t)((b_ * 16 + h_) * 128 + d_) << 11) + s_] = f2b(v);
        } else {
          u16 hv = f2b(v);
          Hdst[(size_t)row * 2048 + col] = hv;
          Ldst[(size_t)row * 2048 + col] = f2b(v - b2f(hv));
        }
      }
    }
  }
}

// ---------- plain GEMM (O-projection): C = A @ B^T + bias, fp32 out ----------
__global__ __launch_bounds__(256) void o_gemm_kernel(
    const u16* __restrict__ Ah, const u16* __restrict__ Bh,
    const float* __restrict__ bias, float* __restrict__ Cf) {
  __shared__ __align__(16) u16 smem[8192];
  u16* sAh = smem;
  u16* sBh = smem + 4096;
  const int t = threadIdx.x;
  const int lane = t & 63, w = t >> 6;
  const int wr = w >> 1, wc = w & 1;
  const int quad = lane >> 4, l16 = lane & 15;
  const int m0 = blockIdx.y * 128, n0 = blockIdx.x * 128;

  f32x4 acc[4][4] = {};

  for (int kt = 0; kt < 64; ++kt) {
#pragma unroll
    for (int j = 0; j < 2; ++j) {
      int c = t + 256 * j;
      int row = c >> 2, cw = c & 3;
      size_t goff = (size_t)row * 2048 + kt * 32 + cw * 8;
      gload16(Ah + (size_t)m0 * 2048 + goff, (char*)sAh + c * 16);
      gload16(Bh + (size_t)n0 * 2048 + goff, (char*)sBh + c * 16);
    }
    __syncthreads();
    bf16x8 ah[4], bh[4];
#pragma unroll
    for (int i = 0; i < 4; ++i) {
      ah[i] = *(const bf16x8*)&sAh[(wr * 64 + i * 16 + l16) * 32 + quad * 8];
      bh[i] = *(const bf16x8*)&sBh[(wc * 64 + i * 16 + l16) * 32 + quad * 8];
    }
#pragma unroll
    for (int mi = 0; mi < 4; ++mi)
#pragma unroll
      for (int ni = 0; ni < 4; ++ni)
        acc[mi][ni] = mfma_bf16(ah[mi], bh[ni], acc[mi][ni]);
    __syncthreads();
  }

#pragma unroll
  for (int mi = 0; mi < 4; ++mi) {
    int rowb = m0 + wr * 64 + mi * 16 + quad * 4;
#pragma unroll
    for (int ni = 0; ni < 4; ++ni) {
      int col = n0 + wc * 64 + ni * 16 + l16;
      float bv = bias[col];
#pragma unroll
      for (int r = 0; r < 4; ++r)
        Cf[(size_t)(rowb + r) * 2048 + col] = acc[mi][ni][r] + bv;
    }
  }
}

// ---------- flash attention v2 (unchanged from measured 1222 us version) ----------
__global__ __launch_bounds__(256, 3) void attn_kernel(
    const u16* __restrict__ Qh, const u16* __restrict__ Ql,
    const u16* __restrict__ Kh, const u16* __restrict__ Kl,
    const u16* __restrict__ VT, const float* __restrict__ bias,
    u16* __restrict__ ctx) {
  // LDS bytes: K[2 buf][hi 8K | lo 8K] = 32768 | V[2 buf][8K] = 16384 | P [64][40] = 5120
  __shared__ __align__(16) u16 sm[27136];  // 54272 B -> 3 blocks/CU
  const int t = threadIdx.x, lane = t & 63, w = t >> 6;
  const int quad = lane >> 4, l16 = lane & 15;
  const int bh = blockIdx.y, b = bh >> 4, h = bh & 15;
  const int q0 = blockIdx.x * 64;

  bf16x8 qh[4], ql[4];
  {
    const size_t qoff =
        (size_t)(b * 2048 + q0 + w * 16 + l16) * 2048 + h * 128 + quad * 8;
#pragma unroll
    for (int ks = 0; ks < 4; ++ks) {
      qh[ks] = *(const bf16x8*)&Qh[qoff + ks * 32];
      ql[ks] = *(const bf16x8*)&Ql[qoff + ks * 32];
    }
  }

  const int kr = t >> 4, kp = (t & 15) ^ (kr & 7);
  const u16* gK = Kh + ((size_t)b * 2048) * 2048 + h * 128 + (size_t)kr * 2048 + kp * 8;
  const int vr = t >> 2, vp = (t & 3) ^ ((vr >> 1) & 3);
  const u16* gV = VT + (size_t)bh * 128 * 2048 + (size_t)vr * 2048 + vp * 8;

  auto stage = [&](int bf, int kt) {
    const u16* pk = gK + (size_t)kt * 65536;
    const u16* pv = gV + kt * 32;
    char* bK = (char*)sm + bf * 16384;
    char* bV = (char*)sm + 32768 + bf * 8192;
    gload16(pk, bK + t * 16);
    gload16(pk + 32768, bK + 4096 + t * 16);
    gload16(pk + 8388608, bK + 8192 + t * 16);
    gload16(pk + 8421376, bK + 12288 + t * 16);
    gload16(pv, bV + t * 16);
    gload16(pv + 131072, bV + 4096 + t * 16);
  };

  f32x4 o[8] = {};
  f32x4 lacc = {};
  float m_i = -3e38f;

  const float* biasp = bias + ((size_t)bh * 2048 + q0 + w * 16 + l16) * 2048;
  bf16x8 ones;
#pragma unroll
  for (int i = 0; i < 8; ++i) ones[i] = __builtin_bit_cast(__bf16, (u16)0x3F80);
  u16* sP = sm + 24576;

  stage(0, 0);
  int buf = 0;

  for (int kt = 0; kt < 64; ++kt) {
    __syncthreads();
    if (kt + 1 < 64) stage(buf ^ 1, kt + 1);
    const int s0 = kt * 32;

    float4 b0 = *(const float4*)&biasp[s0 + quad * 4];
    float4 b1 = *(const float4*)&biasp[s0 + 16 + quad * 4];
    float ba[2][4] = {{b0.x, b0.y, b0.z, b0.w}, {b1.x, b1.y, b1.z, b1.w}};

    const u16* sKh = sm + buf * 8192;
    const u16* sKl = sKh + 4096;
    f32x4 sc[2] = {};
#pragma unroll
    for (int ni = 0; ni < 2; ++ni) {
      const int rb = (ni * 16 + l16) * 128;
      const int x7 = l16 & 7;
#pragma unroll
      for (int ks = 0; ks < 4; ++ks) {
        int koff = rb + (((ks * 4 + quad) ^ x7) << 3);
        bf16x8 kh = *(const bf16x8*)&sKh[koff];
        bf16x8 kl = *(const bf16x8*)&sKl[koff];
        sc[ni] = mfma_bf16(kh, qh[ks], sc[ni]);
        sc[ni] = mfma_bf16(kl, qh[ks], sc[ni]);
        sc[ni] = mfma_bf16(kh, ql[ks], sc[ni]);
      }
    }

    float z[2][4], zm = -3e38f;
#pragma unroll
    for (int ni = 0; ni < 2; ++ni)
#pragma unroll
      for (int r = 0; r < 4; ++r) {
        z[ni][r] = (sc[ni][r] + ba[ni][r]) * LOG2E;
        zm = fmaxf(zm, z[ni][r]);
      }
    zm = fmaxf(zm, __shfl_xor(zm, 16));
    zm = fmaxf(zm, __shfl_xor(zm, 32));

    if (__any(zm > m_i + 11.5416f)) {
      float mn = fmaxf(m_i, zm);
      float alpha = exp2f(m_i - mn);
      m_i = mn;
#pragma unroll
      for (int r = 0; r < 4; ++r) {
        float aC = __shfl(alpha, quad * 4 + r);
        lacc[r] *= aC;
#pragma unroll
        for (int d = 0; d < 8; ++d) o[d][r] *= aC;
      }
    }

    u16* sPw = sP + (w * 16 + l16) * 40 + quad * 4;
#pragma unroll
    for (int ni = 0; ni < 2; ++ni) {
      ushort4 pw;
      pw.x = f2b(exp2f(z[ni][0] - m_i));
      pw.y = f2b(exp2f(z[ni][1] - m_i));
      pw.z = f2b(exp2f(z[ni][2] - m_i));
      pw.w = f2b(exp2f(z[ni][3] - m_i));
      *(ushort4*)&sPw[ni * 16] = pw;
    }

    bf16x8 ap = *(const bf16x8*)&sP[(w * 16 + l16) * 40 + quad * 8];
    lacc = mfma_bf16(ap, ones, lacc);
    const u16* sV = sm + 16384 + buf * 4096;
    const int vx = quad ^ ((l16 >> 1) & 3);
#pragma unroll
    for (int d = 0; d < 8; ++d) {
      bf16x8 bv = *(const bf16x8*)&sV[(d * 16 + l16) * 32 + (vx << 3)];
      o[d] = mfma_bf16(ap, bv, o[d]);
    }
    buf ^= 1;
  }

  float inv[4];
#pragma unroll
  for (int r = 0; r < 4; ++r) inv[r] = 1.f / lacc[r];
#pragma unroll
  for (int d = 0; d < 8; ++d)
#pragma unroll
    for (int r = 0; r < 4; ++r) {
      int qr = w * 16 + quad * 4 + r;
      ctx[((size_t)(b * 2048 + q0 + qr)) * 2048 + h * 128 + d * 16 + l16] =
          f2b(o[d][r] * inv[r]);
    }
}

extern "C" void kernel_launch(void* const* d_in, const int* in_sizes, int n_in,
                              void* d_out, int out_size, void* d_ws, size_t ws_size,
                              hipStream_t stream) {
  (void)in_sizes; (void)n_in; (void)out_size; (void)ws_size;
  const float* x  = (const float*)d_in[0];
  const float* ab = (const float*)d_in[1];
  const float* Wq = (const float*)d_in[2];
  const float* bq = (const float*)d_in[3];
  const float* Wk = (const float*)d_in[4];
  const float* bk = (const float*)d_in[5];
  const float* Wv = (const float*)d_in[6];
  const float* bv = (const float*)d_in[7];
  const float* Wo = (const float*)d_in[8];
  const float* bo = (const float*)d_in[9];
  float* out = (float*)d_out;

  char* ws = (char*)d_ws;
  u16* Kh   = (u16*)(ws + 0);            // bf16 K hi (contiguous with lo: attn relies on it)
  u16* Kl   = (u16*)(ws + 16777216);     // = Kh + 8388608 elems
  u16* VT   = (u16*)(ws + 33554432);     // bf16 V^T [b,h,d,s]
  u16* ctx  = (u16*)(ws + 50331648);     // bf16 ctx [m][hid]
  u16* xh   = (u16*)(ws + 67108864);
  u16* xl   = (u16*)(ws + 83886080);
  u16* WqhT = (u16*)(ws + 100663296);    // 8.4 MB each, all live simultaneously
  u16* WqlT = (u16*)(ws + 109051904);
  u16* WkhT = (u16*)(ws + 117440512);
  u16* WklT = (u16*)(ws + 125829120);
  u16* WvhT = (u16*)(ws + 134217728);
  u16* WohT = (u16*)(ws + 142606336);
  u16* Qh   = (u16*)out;                 // park Q hi/lo in d_out (overwritten by O-GEMM)
  u16* Ql   = (u16*)out + 8388608;

  split_kernel<<<8192, 256, 0, stream>>>(x, xh, xl);

  transpose4_kernel<<<dim3(64, 64, 4), 256, 0, stream>>>(
      Wq, Wk, Wv, Wo, WqhT, WqlT, WkhT, WklT, WvhT, WohT);

  qkv_gemm_kernel<<<dim3(16, 32, 3), 256, 0, stream>>>(
      xh, xl, WqhT, WqlT, WkhT, WklT, WvhT, bq, bk, bv, Qh, Ql, Kh, Kl, VT);

  attn_kernel<<<dim3(32, 32), 256, 0, stream>>>(Qh, Ql, Kh, Kl, VT, ab, ctx);

  o_gemm_kernel<<<dim3(16, 32), 256, 0, stream>>>(ctx, WohT, bo, out);
}